// Round 13
// baseline (2131.774 us; speedup 1.0000x reference)
//
#include <hip/hip_runtime.h>

#define NODE_DIM 128
#define HDIM 64
#define EDGE_DIM 32
#define NB 256          // buckets for CSR binning
#define WMAX 512        // max nodes per bucket (N <= NB*WMAX = 131072)
#define EPB 8192        // edges per block in binning kernels
// packed pair formats: pairD = (dLocal<<23)|src  (src < 2^23)
//                      pairS = (sLocal<<21)|edge (edge < 2^21)

__device__ __forceinline__ void f4_add(float4& a, const float4 b) {
    a.x += b.x; a.y += b.y; a.z += b.z; a.w += b.w;
}
__device__ __forceinline__ void f4_shfl_xor_add(float4& a, int m) {
    a.x += __shfl_xor(a.x, m, 64);
    a.y += __shfl_xor(a.y, m, 64);
    a.z += __shfl_xor(a.z, m, 64);
    a.w += __shfl_xor(a.w, m, 64);
}
__device__ __forceinline__ void f4_fma(float4& a, float s, const float4 w) {
    a.x = fmaf(s, w.x, a.x); a.y = fmaf(s, w.y, a.y);
    a.z = fmaf(s, w.z, a.z); a.w = fmaf(s, w.w, a.w);
}

// ---- pass 1: per-bucket edge counts (dst-keyed and src-keyed) ----
__global__ __launch_bounds__(512) void k_bin_count(const int* __restrict__ src,
        const int* __restrict__ dst, int* __restrict__ countD,
        int* __restrict__ countS, int E, int W) {
    __shared__ int hD[NB], hS[NB];
    int t = threadIdx.x;
    if (t < NB) { hD[t] = 0; hS[t] = 0; }
    __syncthreads();
    int lo = blockIdx.x * EPB, hi = min(lo + EPB, E);
    for (int e = lo + t; e < hi; e += 512) {
        atomicAdd(&hD[dst[e] / W], 1);
        atomicAdd(&hS[src[e] / W], 1);
    }
    __syncthreads();
    if (t < NB) {
        if (hD[t]) atomicAdd(&countD[t], hD[t]);
        if (hS[t]) atomicAdd(&countS[t], hS[t]);
    }
}

// ---- bucket exclusive scan (1 block): bases + mutable cursors ----
__global__ __launch_bounds__(256) void k_bucket_scan(const int* __restrict__ countD,
        const int* __restrict__ countS, int* __restrict__ baseD,
        int* __restrict__ baseS, int* __restrict__ curD, int* __restrict__ curS,
        int E) {
    __shared__ int tmp[NB];
    int t = threadIdx.x;
    int v = countD[t]; tmp[t] = v; __syncthreads();
    for (int off = 1; off < NB; off <<= 1) {
        int u = (t >= off) ? tmp[t - off] : 0; __syncthreads();
        tmp[t] += u; __syncthreads();
    }
    baseD[t] = tmp[t] - v; curD[t] = tmp[t] - v;
    if (t == NB - 1) baseD[NB] = E;
    __syncthreads();
    v = countS[t]; tmp[t] = v; __syncthreads();
    for (int off = 1; off < NB; off <<= 1) {
        int u = (t >= off) ? tmp[t - off] : 0; __syncthreads();
        tmp[t] += u; __syncthreads();
    }
    baseS[t] = tmp[t] - v; curS[t] = tmp[t] - v;
    if (t == NB - 1) baseS[NB] = E;
}

// ---- pass 2: scatter packed pairs into bucket-grouped arrays ----
__global__ __launch_bounds__(512) void k_bin_scatter(const int* __restrict__ src,
        const int* __restrict__ dst, int* __restrict__ curD, int* __restrict__ curS,
        unsigned* __restrict__ pairD, unsigned* __restrict__ pairS, int E, int W) {
    __shared__ int hD[NB], hS[NB], bD[NB], bS[NB], oD[NB], oS[NB];
    int t = threadIdx.x;
    if (t < NB) { hD[t] = 0; hS[t] = 0; oD[t] = 0; oS[t] = 0; }
    __syncthreads();
    int lo = blockIdx.x * EPB, hi = min(lo + EPB, E);
    for (int e = lo + t; e < hi; e += 512) {
        atomicAdd(&hD[dst[e] / W], 1);
        atomicAdd(&hS[src[e] / W], 1);
    }
    __syncthreads();
    if (t < NB) {
        if (hD[t]) bD[t] = atomicAdd(&curD[t], hD[t]);
        if (hS[t]) bS[t] = atomicAdd(&curS[t], hS[t]);
    }
    __syncthreads();
    for (int e = lo + t; e < hi; e += 512) {
        int s = src[e], d = dst[e];
        int kb = d / W;
        int p = bD[kb] + atomicAdd(&oD[kb], 1);
        pairD[p] = ((unsigned)(d - kb * W) << 23) | (unsigned)s;
        kb = s / W;
        p = bS[kb] + atomicAdd(&oS[kb], 1);
        pairS[p] = ((unsigned)(s - kb * W) << 21) | (unsigned)e;
    }
}

// ---- pass 3: per-bucket CSR build (both CSRs in one 512-block launch) ----
__global__ __launch_bounds__(256) void k_build2(const unsigned* __restrict__ pairD,
        const unsigned* __restrict__ pairS, const int* __restrict__ baseD,
        const int* __restrict__ baseS, int* __restrict__ csrD,
        int* __restrict__ csrS, int* __restrict__ rowD, int* __restrict__ rowS,
        float* __restrict__ dinvp, int N, int W) {
    __shared__ int cnt[WMAX], pref[WMAX], cur[WMAX];
    const int half = blockIdx.x >> 8;       // 0: dst-keyed, 1: src-keyed
    const int b = blockIdx.x & (NB - 1);
    const unsigned* pairs = half ? pairS : pairD;
    const int* base = half ? baseS : baseD;
    int* csr = half ? csrS : csrD;
    int* row = half ? rowS : rowD;
    const int shift = half ? 21 : 23;
    const unsigned mask = (1u << shift) - 1u;
    int t = threadIdx.x;
    int nbase = b * W;
    int wlen = min(W, N - nbase);
    int pb = base[b], pe = base[b + 1];
    for (int i = t; i < W; i += 256) cnt[i] = 0;
    __syncthreads();
    for (int j = pb + t; j < pe; j += 256)
        atomicAdd(&cnt[pairs[j] >> shift], 1);
    __syncthreads();
    if (t < 64) {                       // wave0 exclusive scan of cnt[0..W)
        int run = 0;
        for (int c = 0; c < W; c += 64) {
            int i = c + t;
            int v = (i < W) ? cnt[i] : 0;
            int s = v;
            for (int off = 1; off < 64; off <<= 1) {
                int u = __shfl_up(s, off, 64);
                if (t >= off) s += u;
            }
            if (i < W) pref[i] = run + s - v;
            run += __shfl(s, 63, 64);
        }
    }
    __syncthreads();
    for (int i = t; i < wlen; i += 256) {
        row[nbase + i] = pb + pref[i];
        cur[i] = pref[i];
        if (!half) dinvp[nbase + i] = 1.0f / sqrtf((float)cnt[i] + 1.0f);
    }
    if (b == NB - 1 && t == 0) row[N] = base[NB];
    __syncthreads();
    for (int j = pb + t; j < pe; j += 256) {
        unsigned pr = pairs[j];
        int idx = atomicAdd(&cur[pr >> shift], 1);
        csr[pb + idx] = (int)(pr & mask);
    }
}

// ---- fold W_g1 into embed weights: WnF=Wn@W1, WeF=We@W1, bnF=bn@W1, beF=be@W1
__global__ __launch_bounds__(256) void k_foldw(const float* __restrict__ Wn,
        const float* __restrict__ We, const float* __restrict__ bn,
        const float* __restrict__ be, const float* __restrict__ W1,
        float* __restrict__ WnF, float* __restrict__ WeF,
        float* __restrict__ bnF, float* __restrict__ beF) {
    int idx = blockIdx.x * 256 + threadIdx.x;
    int row = idx >> 6, o = idx & 63;
    if (row >= NODE_DIM + EDGE_DIM + 2) return;
    const float* v; float* outp;
    if (row < NODE_DIM)                { v = Wn + row * HDIM; outp = WnF + row * HDIM; }
    else if (row < NODE_DIM + EDGE_DIM){ v = We + (row - NODE_DIM) * HDIM;
                                         outp = WeF + (row - NODE_DIM) * HDIM; }
    else if (row == NODE_DIM + EDGE_DIM){ v = bn; outp = bnF; }
    else                               { v = be; outp = beF; }
    float a = 0.f;
#pragma unroll
    for (int k = 0; k < HDIM; k++) a = fmaf(v[k], W1[k * HDIM + o], a);
    outp[o] = a;
}

// ---- edge-attr segment sum by source: se[n][32]; deep-pipelined gather ----
__global__ __launch_bounds__(256) void k_edge_sum(const float* __restrict__ ea,
        const int* __restrict__ csr_out_e, const int* __restrict__ row_out,
        float* __restrict__ se, int n) {
    int g = threadIdx.x >> 6, lane = threadIdx.x & 63;
    int slot = lane >> 3, dq = lane & 7;
    int node = blockIdx.x * 4 + g;
    if (node >= n) return;
    int jb = row_out[node], je = row_out[node + 1];
    float4 acc = make_float4(0.f, 0.f, 0.f, 0.f);
    for (int base = jb; base < je; base += 64) {
        int cnt = min(64, je - base);
        int myidx = (base + lane < je) ? csr_out_e[base + lane] : 0;
        int t = 0;
#pragma unroll 2
        for (; t + 16 <= cnt; t += 16) {        // unpredicated: 2 edges/slot/iter
            int e0 = __shfl(myidx, t + slot, 64);
            int e1 = __shfl(myidx, t + 8 + slot, 64);
            float4 v0 = *reinterpret_cast<const float4*>(
                &ea[(size_t)e0 * EDGE_DIM + 4 * dq]);
            float4 v1 = *reinterpret_cast<const float4*>(
                &ea[(size_t)e1 * EDGE_DIM + 4 * dq]);
            f4_add(acc, v0);
            f4_add(acc, v1);
        }
        for (; t < cnt; t += 8) {               // predicated tail
            int which = t + slot;
            int e = __shfl(myidx, which, 64);
            if (which < cnt) {
                float4 v = *reinterpret_cast<const float4*>(
                    &ea[(size_t)e * EDGE_DIM + 4 * dq]);
                f4_add(acc, v);
            }
        }
    }
    f4_shfl_xor_add(acc, 8);
    f4_shfl_xor_add(acc, 16);
    f4_shfl_xor_add(acc, 32);
    if (slot == 0)
        *reinterpret_cast<float4*>(&se[(size_t)node * EDGE_DIM + 4 * dq]) = acc;
}

// ---- embed GEMM, split-K W/x staging (folded W_g1, K=160), 3 blk/CU:
// g1 = dinv * ( x@WnF + se@WeF + bnF + outdeg*beF )
// 64-node tile/block; 256 thr = 8 o-thr x 32 m-thr; thread = 2 nodes x 8 outs
__global__ __launch_bounds__(256) void k_embed_g1w(const float* __restrict__ x,
        const float* __restrict__ se, const int* __restrict__ row_out,
        const float* __restrict__ dinv,
        const float* __restrict__ WnF, const float* __restrict__ WeF,
        const float* __restrict__ bnF, const float* __restrict__ beF,
        float* __restrict__ gout, int N) {
    __shared__ float wnh[64][HDIM];        // 16 KB (one K-half of WnF)
    __shared__ float xs[64][68];           // 17.4 KB (one K-half of x tile)
    __shared__ float ses[64][36];          // 9.2 KB
    __shared__ float dv[64], od[64];       // -> total 42.5 KB, 3 blk/CU
    const int tid = threadIdx.x;
    const int node0 = blockIdx.x * 64;
    const int o0 = (tid & 7) * 8;
    const int m0 = (tid >> 3) * 2;

    // ---- stage ses, dv, od once ----
#pragma unroll
    for (int r = 0; r < 2; r++) {
        int idx = r * 256 + tid;
        int m = idx >> 3, c4 = (idx & 7) * 4;
        if (node0 + m < N)
            *reinterpret_cast<float4*>(&ses[m][c4]) =
                *reinterpret_cast<const float4*>(&se[(size_t)(node0 + m) * EDGE_DIM + c4]);
    }
    if (tid < 64) {
        int nd = node0 + tid;
        if (nd < N) {
            dv[tid] = dinv[nd];
            od[tid] = (float)(row_out[nd + 1] - row_out[nd]);
        } else { dv[tid] = 0.f; od[tid] = 0.f; }
    }

    float4 acc[2][2];
    bool first = true;
    for (int half = 0; half < 2; half++) {
        if (!first) __syncthreads();     // protect LDS reuse
        // stage this K-half of WnF (64 rows) and x (64 cols per node)
        {
            const float4* s4 = reinterpret_cast<const float4*>(WnF + half * 64 * HDIM);
            float4* d4 = reinterpret_cast<float4*>(&wnh[0][0]);
#pragma unroll
            for (int r = 0; r < 4; r++) d4[r * 256 + tid] = s4[r * 256 + tid];
        }
#pragma unroll
        for (int r = 0; r < 4; r++) {
            int idx = r * 256 + tid;
            int m = idx >> 4, c4 = (idx & 15) * 4;
            if (node0 + m < N)
                *reinterpret_cast<float4*>(&xs[m][c4]) =
                    *reinterpret_cast<const float4*>(
                        &x[(size_t)(node0 + m) * NODE_DIM + half * 64 + c4]);
        }
        __syncthreads();
        if (first) {                     // init acc with biases (od now visible)
            float4 bna = *reinterpret_cast<const float4*>(&bnF[o0]);
            float4 bnb = *reinterpret_cast<const float4*>(&bnF[o0 + 4]);
            float4 bea = *reinterpret_cast<const float4*>(&beF[o0]);
            float4 beb = *reinterpret_cast<const float4*>(&beF[o0 + 4]);
#pragma unroll
            for (int i = 0; i < 2; i++) {
                float odv = od[m0 + i];
                acc[i][0] = make_float4(fmaf(odv, bea.x, bna.x), fmaf(odv, bea.y, bna.y),
                                        fmaf(odv, bea.z, bna.z), fmaf(odv, bea.w, bna.w));
                acc[i][1] = make_float4(fmaf(odv, beb.x, bnb.x), fmaf(odv, beb.y, bnb.y),
                                        fmaf(odv, beb.z, bnb.z), fmaf(odv, beb.w, bnb.w));
            }
            first = false;
        }
        for (int k = 0; k < 64; k += 4) {
            float4 xv0 = *reinterpret_cast<const float4*>(&xs[m0][k]);
            float4 xv1 = *reinterpret_cast<const float4*>(&xs[m0 + 1][k]);
            float x0v[4] = {xv0.x, xv0.y, xv0.z, xv0.w};
            float x1v[4] = {xv1.x, xv1.y, xv1.z, xv1.w};
#pragma unroll
            for (int j = 0; j < 4; j++) {
                float4 wa = *reinterpret_cast<const float4*>(&wnh[k + j][o0]);
                float4 wb = *reinterpret_cast<const float4*>(&wnh[k + j][o0 + 4]);
                f4_fma(acc[0][0], x0v[j], wa); f4_fma(acc[0][1], x0v[j], wb);
                f4_fma(acc[1][0], x1v[j], wa); f4_fma(acc[1][1], x1v[j], wb);
            }
        }
    }
    // ses @ WeF (global broadcast reads, L1-resident)
    for (int k = 0; k < EDGE_DIM; k += 4) {
        float4 sv0 = *reinterpret_cast<const float4*>(&ses[m0][k]);
        float4 sv1 = *reinterpret_cast<const float4*>(&ses[m0 + 1][k]);
        float s0v[4] = {sv0.x, sv0.y, sv0.z, sv0.w};
        float s1v[4] = {sv1.x, sv1.y, sv1.z, sv1.w};
#pragma unroll
        for (int j = 0; j < 4; j++) {
            float4 wa = *reinterpret_cast<const float4*>(&WeF[(k + j) * HDIM + o0]);
            float4 wb = *reinterpret_cast<const float4*>(&WeF[(k + j) * HDIM + o0 + 4]);
            f4_fma(acc[0][0], s0v[j], wa); f4_fma(acc[0][1], s0v[j], wb);
            f4_fma(acc[1][0], s1v[j], wa); f4_fma(acc[1][1], s1v[j], wb);
        }
    }
#pragma unroll
    for (int i = 0; i < 2; i++) {
        int node = node0 + m0 + i;
        if (node < N) {
            float d = dv[m0 + i];
            float4 r0 = acc[i][0], r1 = acc[i][1];
            r0.x *= d; r0.y *= d; r0.z *= d; r0.w *= d;
            r1.x *= d; r1.y *= d; r1.z *= d; r1.w *= d;
            *reinterpret_cast<float4*>(&gout[(size_t)node * HDIM + o0])     = r0;
            *reinterpret_cast<float4*>(&gout[(size_t)node * HDIM + o0 + 4]) = r1;
        }
    }
}

// ---- fused gather + next-layer matmul (8 slots x 8 lanes: 16 rows in flight) ----
__global__ __launch_bounds__(256) void k_gather_mm(const int* __restrict__ csr_src,
        const int* __restrict__ row_in, const float* __restrict__ gbuf,
        const float* __restrict__ bin, const float* __restrict__ dinv,
        const float* __restrict__ W, float* __restrict__ gout, int n) {
    __shared__ float hs[4][HDIM];
    int g = threadIdx.x >> 6, lane = threadIdx.x & 63;
    int slot = lane >> 3, dq8 = (lane & 7) * 8;
    int node = blockIdx.x * 4 + g;
    bool valid = node < n;
    float di = 0.f;
    float4 a0 = make_float4(0.f, 0.f, 0.f, 0.f);
    float4 a1 = make_float4(0.f, 0.f, 0.f, 0.f);
    if (valid) {
        di = dinv[node];
        if (slot == 0) {
            a0 = *reinterpret_cast<const float4*>(&gbuf[(size_t)node * HDIM + dq8]);
            a1 = *reinterpret_cast<const float4*>(&gbuf[(size_t)node * HDIM + dq8 + 4]);
        }
        int jb = row_in[node], je = row_in[node + 1];
        for (int base = jb; base < je; base += 64) {
            int cnt = min(64, je - base);
            int myidx = (base + lane < je) ? csr_src[base + lane] : 0;
            int t = 0;
#pragma unroll 2
            for (; t + 16 <= cnt; t += 16) {   // unpredicated: 2 rows/slot/iter
                int e0 = __shfl(myidx, t + slot, 64);
                int e1 = __shfl(myidx, t + 8 + slot, 64);
                const float* r0 = &gbuf[(size_t)e0 * HDIM + dq8];
                const float* r1 = &gbuf[(size_t)e1 * HDIM + dq8];
                float4 v00 = *reinterpret_cast<const float4*>(r0);
                float4 v01 = *reinterpret_cast<const float4*>(r0 + 4);
                float4 v10 = *reinterpret_cast<const float4*>(r1);
                float4 v11 = *reinterpret_cast<const float4*>(r1 + 4);
                f4_add(a0, v00); f4_add(a1, v01);
                f4_add(a0, v10); f4_add(a1, v11);
            }
            for (; t < cnt; t += 8) {          // predicated tail
                int which = t + slot;
                int e = __shfl(myidx, which, 64);
                if (which < cnt) {
                    const float* r = &gbuf[(size_t)e * HDIM + dq8];
                    f4_add(a0, *reinterpret_cast<const float4*>(r));
                    f4_add(a1, *reinterpret_cast<const float4*>(r + 4));
                }
            }
        }
        f4_shfl_xor_add(a0, 8);  f4_shfl_xor_add(a1, 8);
        f4_shfl_xor_add(a0, 16); f4_shfl_xor_add(a1, 16);
        f4_shfl_xor_add(a0, 32); f4_shfl_xor_add(a1, 32);
        if (slot == 0) {
            float4 b0 = *reinterpret_cast<const float4*>(&bin[dq8]);
            float4 b1 = *reinterpret_cast<const float4*>(&bin[dq8 + 4]);
            float4 z0, z1;
            z0.x = fmaxf(fmaf(di, a0.x, b0.x), 0.f);
            z0.y = fmaxf(fmaf(di, a0.y, b0.y), 0.f);
            z0.z = fmaxf(fmaf(di, a0.z, b0.z), 0.f);
            z0.w = fmaxf(fmaf(di, a0.w, b0.w), 0.f);
            z1.x = fmaxf(fmaf(di, a1.x, b1.x), 0.f);
            z1.y = fmaxf(fmaf(di, a1.y, b1.y), 0.f);
            z1.z = fmaxf(fmaf(di, a1.z, b1.z), 0.f);
            z1.w = fmaxf(fmaf(di, a1.w, b1.w), 0.f);
            *reinterpret_cast<float4*>(&hs[g][dq8])     = z0;
            *reinterpret_cast<float4*>(&hs[g][dq8 + 4]) = z1;
        }
    }
    __syncthreads();
    if (!valid) return;
    float a = 0.f;
#pragma unroll
    for (int k = 0; k < HDIM; k++) a = fmaf(hs[g][k], W[k * HDIM + lane], a);
    gout[(size_t)node * HDIM + lane] = a * di;
}

// ---- conv3 gather + finalize + mean-pool (8x8 decomposition, merged atomics) ----
__global__ __launch_bounds__(256) void k_gather_pool(const int* __restrict__ csr_src,
        const int* __restrict__ row_in, const float* __restrict__ gbuf,
        const float* __restrict__ bin, const float* __restrict__ dinv,
        const int* __restrict__ batch, float* __restrict__ sums,
        float* __restrict__ cnts, int n) {
    __shared__ float vs[4][HDIM];
    __shared__ int bs[4];
    int g = threadIdx.x >> 6, lane = threadIdx.x & 63;
    int slot = lane >> 3, dq8 = (lane & 7) * 8;
    int node = blockIdx.x * 4 + g;
    bool valid = node < n;
    float di = 0.f;
    int b = -1;
    float4 a0 = make_float4(0.f, 0.f, 0.f, 0.f);
    float4 a1 = make_float4(0.f, 0.f, 0.f, 0.f);
    if (valid) {
        di = dinv[node];
        b = batch[node];
        if (slot == 0) {
            a0 = *reinterpret_cast<const float4*>(&gbuf[(size_t)node * HDIM + dq8]);
            a1 = *reinterpret_cast<const float4*>(&gbuf[(size_t)node * HDIM + dq8 + 4]);
        }
        int jb = row_in[node], je = row_in[node + 1];
        for (int base = jb; base < je; base += 64) {
            int cnt = min(64, je - base);
            int myidx = (base + lane < je) ? csr_src[base + lane] : 0;
            int t = 0;
#pragma unroll 2
            for (; t + 16 <= cnt; t += 16) {
                int e0 = __shfl(myidx, t + slot, 64);
                int e1 = __shfl(myidx, t + 8 + slot, 64);
                const float* r0 = &gbuf[(size_t)e0 * HDIM + dq8];
                const float* r1 = &gbuf[(size_t)e1 * HDIM + dq8];
                float4 v00 = *reinterpret_cast<const float4*>(r0);
                float4 v01 = *reinterpret_cast<const float4*>(r0 + 4);
                float4 v10 = *reinterpret_cast<const float4*>(r1);
                float4 v11 = *reinterpret_cast<const float4*>(r1 + 4);
                f4_add(a0, v00); f4_add(a1, v01);
                f4_add(a0, v10); f4_add(a1, v11);
            }
            for (; t < cnt; t += 8) {
                int which = t + slot;
                int e = __shfl(myidx, which, 64);
                if (which < cnt) {
                    const float* r = &gbuf[(size_t)e * HDIM + dq8];
                    f4_add(a0, *reinterpret_cast<const float4*>(r));
                    f4_add(a1, *reinterpret_cast<const float4*>(r + 4));
                }
            }
        }
        f4_shfl_xor_add(a0, 8);  f4_shfl_xor_add(a1, 8);
        f4_shfl_xor_add(a0, 16); f4_shfl_xor_add(a1, 16);
        f4_shfl_xor_add(a0, 32); f4_shfl_xor_add(a1, 32);
        if (slot == 0) {
            float4 b0 = *reinterpret_cast<const float4*>(&bin[dq8]);
            float4 b1 = *reinterpret_cast<const float4*>(&bin[dq8 + 4]);
            float4 z0, z1;
            z0.x = fmaf(di, a0.x, b0.x); z0.y = fmaf(di, a0.y, b0.y);
            z0.z = fmaf(di, a0.z, b0.z); z0.w = fmaf(di, a0.w, b0.w);
            z1.x = fmaf(di, a1.x, b1.x); z1.y = fmaf(di, a1.y, b1.y);
            z1.z = fmaf(di, a1.z, b1.z); z1.w = fmaf(di, a1.w, b1.w);
            *reinterpret_cast<float4*>(&vs[g][dq8])     = z0;
            *reinterpret_cast<float4*>(&vs[g][dq8 + 4]) = z1;
        }
    }
    if (lane == 0) bs[g] = b;
    __syncthreads();
    bool same = (bs[0] >= 0 && bs[0] == bs[1] && bs[1] == bs[2] && bs[2] == bs[3]);
    if (same) {
        if (g == 0) {
            float t = vs[0][lane] + vs[1][lane] + vs[2][lane] + vs[3][lane];
            atomicAdd(&sums[(size_t)bs[0] * HDIM + lane], t);
            if (lane == 0) atomicAdd(&cnts[bs[0]], 4.0f);
        }
    } else if (valid) {
        atomicAdd(&sums[(size_t)b * HDIM + lane], vs[g][lane]);
        if (lane == 0) atomicAdd(&cnts[b], 1.0f);
    }
}

// ---- classifier ----
__global__ __launch_bounds__(64) void k_cls(const float* __restrict__ sums,
        const float* __restrict__ cnts, const float* __restrict__ W1,
        const float* __restrict__ b1, const float* __restrict__ W2,
        const float* __restrict__ b2, float* __restrict__ out) {
    __shared__ float gs[HDIM];
    __shared__ float zs[32];
    int b = blockIdx.x, t = threadIdx.x;
    float cnt = fmaxf(cnts[b], 1.0f);
    gs[t] = sums[(size_t)b * HDIM + t] / cnt;
    __syncthreads();
    if (t < 32) {
        float a = b1[t];
#pragma unroll
        for (int k = 0; k < HDIM; k++) a = fmaf(gs[k], W1[k * 32 + t], a);
        zs[t] = fmaxf(a, 0.0f);
    }
    __syncthreads();
    if (t == 0) {
        float a = b2[0];
#pragma unroll
        for (int k = 0; k < 32; k++) a = fmaf(zs[k], W2[k], a);
        out[b] = a;
    }
}

extern "C" void kernel_launch(void* const* d_in, const int* in_sizes, int n_in,
                              void* d_out, int out_size, void* d_ws, size_t ws_size,
                              hipStream_t stream) {
    const float* x      = (const float*)d_in[0];
    const int*   ei     = (const int*)d_in[1];
    const float* ea     = (const float*)d_in[2];
    const int*   batch  = (const int*)d_in[3];
    const float* W_node = (const float*)d_in[4];
    const float* b_node = (const float*)d_in[5];
    const float* W_edge = (const float*)d_in[6];
    const float* b_edge = (const float*)d_in[7];
    const float* W_g1   = (const float*)d_in[8];
    const float* b_g1   = (const float*)d_in[9];
    const float* W_g2   = (const float*)d_in[10];
    const float* b_g2   = (const float*)d_in[11];
    const float* W_g3   = (const float*)d_in[12];
    const float* b_g3   = (const float*)d_in[13];
    const float* W_c1   = (const float*)d_in[14];
    const float* b_c1   = (const float*)d_in[15];
    const float* W_c2   = (const float*)d_in[16];
    const float* b_c2   = (const float*)d_in[17];

    const int N = in_sizes[0] / NODE_DIM;
    const int E = in_sizes[2] / EDGE_DIM;
    const int G = out_size;
    const int W = (N + NB - 1) / NB;
    const int* src = ei;
    const int* dst = ei + E;

    char* ws = (char*)d_ws;
    size_t off = 0;
    auto carve = [&](size_t bytes) -> void* {
        void* p = ws + off;
        off += (bytes + 255) & ~(size_t)255;
        return p;
    };
    int*   counts     = (int*)carve((size_t)2 * NB * 4);
    int*   baseD      = (int*)carve((size_t)(NB + 1) * 4);
    int*   baseS      = (int*)carve((size_t)(NB + 1) * 4);
    int*   curD       = (int*)carve((size_t)NB * 4);
    int*   curS       = (int*)carve((size_t)NB * 4);
    int*   row_in     = (int*)carve((size_t)(N + 1) * 4);
    int*   row_out    = (int*)carve((size_t)(N + 1) * 4);
    int*   csr_in_src = (int*)carve((size_t)E * 4);
    int*   csr_out_e  = (int*)carve((size_t)E * 4);
    float* dinv       = (float*)carve((size_t)N * 4);
    float* se         = (float*)carve((size_t)N * EDGE_DIM * 4);
    float* B          = (float*)carve((size_t)N * HDIM * 4);
    float* C          = (float*)carve((size_t)N * HDIM * 4);
    float* sums       = (float*)carve((size_t)G * HDIM * 4);
    float* cnts       = (float*)carve((size_t)G * 4);
    float* WnF        = (float*)carve((size_t)NODE_DIM * HDIM * 4);
    float* WeF        = (float*)carve((size_t)EDGE_DIM * HDIM * 4);
    float* bnF        = (float*)carve((size_t)HDIM * 4);
    float* beF        = (float*)carve((size_t)HDIM * 4);
    int*   countD = counts, *countS = counts + NB;
    unsigned* pairD = (unsigned*)B;   // aliases B (consumed before B first written)
    unsigned* pairS = (unsigned*)C;   // aliases C

    hipMemsetAsync(counts, 0, (size_t)2 * NB * 4, stream);
    hipMemsetAsync(sums, 0, (size_t)G * HDIM * 4, stream);
    hipMemsetAsync(cnts, 0, (size_t)G * 4, stream);

    const int nb_nodes = (N + 3) / 4;
    const int nb_bin   = (E + EPB - 1) / EPB;
    const int nb_t64   = (N + 63) / 64;

    // fold W_g1 into the embed weights (independent of graph build)
    k_foldw<<<((NODE_DIM + EDGE_DIM + 2) * HDIM + 255) / 256, 256, 0, stream>>>(
        W_node, W_edge, b_node, b_edge, W_g1, WnF, WeF, bnF, beF);

    // CSR construction via bucket binning (packed pairs, merged build)
    k_bin_count<<<nb_bin, 512, 0, stream>>>(src, dst, countD, countS, E, W);
    k_bucket_scan<<<1, 256, 0, stream>>>(countD, countS, baseD, baseS, curD, curS, E);
    k_bin_scatter<<<nb_bin, 512, 0, stream>>>(src, dst, curD, curS, pairD, pairS, E, W);
    k_build2<<<2 * NB, 256, 0, stream>>>(pairD, pairS, baseD, baseS,
                                         csr_in_src, csr_out_e, row_in, row_out,
                                         dinv, N, W);

    // edge-attr segment sum, then split-K W-in-LDS fused embed -> B (g1)
    k_edge_sum<<<nb_nodes, 256, 0, stream>>>(ea, csr_out_e, row_out, se, N);
    k_embed_g1w<<<nb_t64, 256, 0, stream>>>(x, se, row_out, dinv, WnF, WeF, bnF, beF,
                                            B, N);

    // conv1 gather + mm2 -> C (g2); conv2 gather + mm3 -> B (g3)
    k_gather_mm<<<nb_nodes, 256, 0, stream>>>(csr_in_src, row_in, B, b_g1, dinv,
                                              W_g2, C, N);
    k_gather_mm<<<nb_nodes, 256, 0, stream>>>(csr_in_src, row_in, C, b_g2, dinv,
                                              W_g3, B, N);

    // conv3 gather + finalize + pool, then classifier
    k_gather_pool<<<nb_nodes, 256, 0, stream>>>(csr_in_src, row_in, B, b_g3,
                                                dinv, batch, sums, cnts, N);
    k_cls<<<G, 64, 0, stream>>>(sums, cnts, W_c1, b_c1, W_c2, b_c2, (float*)d_out);
}

// Round 14
// 492.340 us; speedup vs baseline: 4.3299x; 4.3299x over previous
//
#include <hip/hip_runtime.h>

#define NODE_DIM 128
#define HDIM 64
#define EDGE_DIM 32
#define NB 256          // buckets for CSR binning
#define WMAX 512        // max nodes per bucket (N <= NB*WMAX = 131072)
#define EPB 8192        // edges per block in binning kernels
// packed pair formats: pairD = (dLocal<<23)|src  (src < 2^23)
//                      pairS = (sLocal<<21)|edge (edge < 2^21)

__device__ __forceinline__ void f4_add(float4& a, const float4 b) {
    a.x += b.x; a.y += b.y; a.z += b.z; a.w += b.w;
}
__device__ __forceinline__ void f4_shfl_xor_add(float4& a, int m) {
    a.x += __shfl_xor(a.x, m, 64);
    a.y += __shfl_xor(a.y, m, 64);
    a.z += __shfl_xor(a.z, m, 64);
    a.w += __shfl_xor(a.w, m, 64);
}
__device__ __forceinline__ void f4_fma(float4& a, float s, const float4 w) {
    a.x = fmaf(s, w.x, a.x); a.y = fmaf(s, w.y, a.y);
    a.z = fmaf(s, w.z, a.z); a.w = fmaf(s, w.w, a.w);
}

// ---- pass 1: per-bucket edge counts (dst-keyed and src-keyed) ----
__global__ __launch_bounds__(512) void k_bin_count(const int* __restrict__ src,
        const int* __restrict__ dst, int* __restrict__ countD,
        int* __restrict__ countS, int E, int W) {
    __shared__ int hD[NB], hS[NB];
    int t = threadIdx.x;
    if (t < NB) { hD[t] = 0; hS[t] = 0; }
    __syncthreads();
    int lo = blockIdx.x * EPB, hi = min(lo + EPB, E);
    for (int e = lo + t; e < hi; e += 512) {
        atomicAdd(&hD[dst[e] / W], 1);
        atomicAdd(&hS[src[e] / W], 1);
    }
    __syncthreads();
    if (t < NB) {
        if (hD[t]) atomicAdd(&countD[t], hD[t]);
        if (hS[t]) atomicAdd(&countS[t], hS[t]);
    }
}

// ---- bucket exclusive scan (1 block): bases + mutable cursors ----
__global__ __launch_bounds__(256) void k_bucket_scan(const int* __restrict__ countD,
        const int* __restrict__ countS, int* __restrict__ baseD,
        int* __restrict__ baseS, int* __restrict__ curD, int* __restrict__ curS,
        int E) {
    __shared__ int tmp[NB];
    int t = threadIdx.x;
    int v = countD[t]; tmp[t] = v; __syncthreads();
    for (int off = 1; off < NB; off <<= 1) {
        int u = (t >= off) ? tmp[t - off] : 0; __syncthreads();
        tmp[t] += u; __syncthreads();
    }
    baseD[t] = tmp[t] - v; curD[t] = tmp[t] - v;
    if (t == NB - 1) baseD[NB] = E;
    __syncthreads();
    v = countS[t]; tmp[t] = v; __syncthreads();
    for (int off = 1; off < NB; off <<= 1) {
        int u = (t >= off) ? tmp[t - off] : 0; __syncthreads();
        tmp[t] += u; __syncthreads();
    }
    baseS[t] = tmp[t] - v; curS[t] = tmp[t] - v;
    if (t == NB - 1) baseS[NB] = E;
}

// ---- pass 2: scatter packed pairs into bucket-grouped arrays ----
__global__ __launch_bounds__(512) void k_bin_scatter(const int* __restrict__ src,
        const int* __restrict__ dst, int* __restrict__ curD, int* __restrict__ curS,
        unsigned* __restrict__ pairD, unsigned* __restrict__ pairS, int E, int W) {
    __shared__ int hD[NB], hS[NB], bD[NB], bS[NB], oD[NB], oS[NB];
    int t = threadIdx.x;
    if (t < NB) { hD[t] = 0; hS[t] = 0; oD[t] = 0; oS[t] = 0; }
    __syncthreads();
    int lo = blockIdx.x * EPB, hi = min(lo + EPB, E);
    for (int e = lo + t; e < hi; e += 512) {
        atomicAdd(&hD[dst[e] / W], 1);
        atomicAdd(&hS[src[e] / W], 1);
    }
    __syncthreads();
    if (t < NB) {
        if (hD[t]) bD[t] = atomicAdd(&curD[t], hD[t]);
        if (hS[t]) bS[t] = atomicAdd(&curS[t], hS[t]);
    }
    __syncthreads();
    for (int e = lo + t; e < hi; e += 512) {
        int s = src[e], d = dst[e];
        int kb = d / W;
        int p = bD[kb] + atomicAdd(&oD[kb], 1);
        pairD[p] = ((unsigned)(d - kb * W) << 23) | (unsigned)s;
        kb = s / W;
        p = bS[kb] + atomicAdd(&oS[kb], 1);
        pairS[p] = ((unsigned)(s - kb * W) << 21) | (unsigned)e;
    }
}

// ---- pass 3: per-bucket CSR build (both CSRs in one 512-block launch) ----
__global__ __launch_bounds__(256) void k_build2(const unsigned* __restrict__ pairD,
        const unsigned* __restrict__ pairS, const int* __restrict__ baseD,
        const int* __restrict__ baseS, int* __restrict__ csrD,
        int* __restrict__ csrS, int* __restrict__ rowD, int* __restrict__ rowS,
        float* __restrict__ dinvp, int N, int W) {
    __shared__ int cnt[WMAX], pref[WMAX], cur[WMAX];
    const int half = blockIdx.x >> 8;       // 0: dst-keyed, 1: src-keyed
    const int b = blockIdx.x & (NB - 1);
    const unsigned* pairs = half ? pairS : pairD;
    const int* base = half ? baseS : baseD;
    int* csr = half ? csrS : csrD;
    int* row = half ? rowS : rowD;
    const int shift = half ? 21 : 23;
    const unsigned mask = (1u << shift) - 1u;
    int t = threadIdx.x;
    int nbase = b * W;
    int wlen = min(W, N - nbase);
    int pb = base[b], pe = base[b + 1];
    for (int i = t; i < W; i += 256) cnt[i] = 0;
    __syncthreads();
    for (int j = pb + t; j < pe; j += 256)
        atomicAdd(&cnt[pairs[j] >> shift], 1);
    __syncthreads();
    if (t < 64) {                       // wave0 exclusive scan of cnt[0..W)
        int run = 0;
        for (int c = 0; c < W; c += 64) {
            int i = c + t;
            int v = (i < W) ? cnt[i] : 0;
            int s = v;
            for (int off = 1; off < 64; off <<= 1) {
                int u = __shfl_up(s, off, 64);
                if (t >= off) s += u;
            }
            if (i < W) pref[i] = run + s - v;
            run += __shfl(s, 63, 64);
        }
    }
    __syncthreads();
    for (int i = t; i < wlen; i += 256) {
        row[nbase + i] = pb + pref[i];
        cur[i] = pref[i];
        if (!half) dinvp[nbase + i] = 1.0f / sqrtf((float)cnt[i] + 1.0f);
    }
    if (b == NB - 1 && t == 0) row[N] = base[NB];
    __syncthreads();
    for (int j = pb + t; j < pe; j += 256) {
        unsigned pr = pairs[j];
        int idx = atomicAdd(&cur[pr >> shift], 1);
        csr[pb + idx] = (int)(pr & mask);
    }
}

// ---- fold W_g1 into embed weights: WnF=Wn@W1, WeF=We@W1, bnF=bn@W1, beF=be@W1
__global__ __launch_bounds__(256) void k_foldw(const float* __restrict__ Wn,
        const float* __restrict__ We, const float* __restrict__ bn,
        const float* __restrict__ be, const float* __restrict__ W1,
        float* __restrict__ WnF, float* __restrict__ WeF,
        float* __restrict__ bnF, float* __restrict__ beF) {
    int idx = blockIdx.x * 256 + threadIdx.x;
    int row = idx >> 6, o = idx & 63;
    if (row >= NODE_DIM + EDGE_DIM + 2) return;
    const float* v; float* outp;
    if (row < NODE_DIM)                { v = Wn + row * HDIM; outp = WnF + row * HDIM; }
    else if (row < NODE_DIM + EDGE_DIM){ v = We + (row - NODE_DIM) * HDIM;
                                         outp = WeF + (row - NODE_DIM) * HDIM; }
    else if (row == NODE_DIM + EDGE_DIM){ v = bn; outp = bnF; }
    else                               { v = be; outp = beF; }
    float a = 0.f;
#pragma unroll
    for (int k = 0; k < HDIM; k++) a = fmaf(v[k], W1[k * HDIM + o], a);
    outp[o] = a;
}

// ---- edge-attr segment sum by source: se[n][32]; deep-pipelined gather ----
__global__ __launch_bounds__(256) void k_edge_sum(const float* __restrict__ ea,
        const int* __restrict__ csr_out_e, const int* __restrict__ row_out,
        float* __restrict__ se, int n) {
    int g = threadIdx.x >> 6, lane = threadIdx.x & 63;
    int slot = lane >> 3, dq = lane & 7;
    int node = blockIdx.x * 4 + g;
    if (node >= n) return;
    int jb = row_out[node], je = row_out[node + 1];
    float4 acc = make_float4(0.f, 0.f, 0.f, 0.f);
    for (int base = jb; base < je; base += 64) {
        int cnt = min(64, je - base);
        int myidx = (base + lane < je) ? csr_out_e[base + lane] : 0;
        int t = 0;
#pragma unroll 2
        for (; t + 16 <= cnt; t += 16) {        // unpredicated: 2 edges/slot/iter
            int e0 = __shfl(myidx, t + slot, 64);
            int e1 = __shfl(myidx, t + 8 + slot, 64);
            float4 v0 = *reinterpret_cast<const float4*>(
                &ea[(size_t)e0 * EDGE_DIM + 4 * dq]);
            float4 v1 = *reinterpret_cast<const float4*>(
                &ea[(size_t)e1 * EDGE_DIM + 4 * dq]);
            f4_add(acc, v0);
            f4_add(acc, v1);
        }
        for (; t < cnt; t += 8) {               // predicated tail
            int which = t + slot;
            int e = __shfl(myidx, which, 64);
            if (which < cnt) {
                float4 v = *reinterpret_cast<const float4*>(
                    &ea[(size_t)e * EDGE_DIM + 4 * dq]);
                f4_add(acc, v);
            }
        }
    }
    f4_shfl_xor_add(acc, 8);
    f4_shfl_xor_add(acc, 16);
    f4_shfl_xor_add(acc, 32);
    if (slot == 0)
        *reinterpret_cast<float4*>(&se[(size_t)node * EDGE_DIM + 4 * dq]) = acc;
}

// ---- embed GEMM, W in LDS + 2 nodes/thread (folded W_g1, K=160) — R10-proven:
// g1 = dinv * ( x@WnF + se@WeF + bnF + outdeg*beF )
__global__ __launch_bounds__(256) void k_embed_g1w(const float* __restrict__ x,
        const float* __restrict__ se, const int* __restrict__ row_out,
        const float* __restrict__ dinv,
        const float* __restrict__ WnF, const float* __restrict__ WeF,
        const float* __restrict__ bnF, const float* __restrict__ beF,
        float* __restrict__ gout, int N) {
    __shared__ float wn[NODE_DIM][HDIM];   // 32 KB
    __shared__ float xs[64][132];          // 33.8 KB (pad: 528B rows)
    __shared__ float ses[64][36];          // 9.2 KB
    __shared__ float dv[64], od[64];       // -> total 76.8 KB, 2 blk/CU
    const int tid = threadIdx.x;
    const int node0 = blockIdx.x * 64;
    const int o0 = (tid & 7) * 8;
    const int m0 = (tid >> 3) * 2;

    {
        const float4* s4 = reinterpret_cast<const float4*>(WnF);
        float4* d4 = reinterpret_cast<float4*>(&wn[0][0]);
#pragma unroll
        for (int r = 0; r < 8; r++) d4[r * 256 + tid] = s4[r * 256 + tid];
    }
#pragma unroll
    for (int r = 0; r < 8; r++) {
        int idx = r * 256 + tid;
        int m = idx >> 5, c4 = (idx & 31) * 4;
        if (node0 + m < N)
            *reinterpret_cast<float4*>(&xs[m][c4]) =
                *reinterpret_cast<const float4*>(&x[(size_t)(node0 + m) * NODE_DIM + c4]);
    }
#pragma unroll
    for (int r = 0; r < 2; r++) {
        int idx = r * 256 + tid;
        int m = idx >> 3, c4 = (idx & 7) * 4;
        if (node0 + m < N)
            *reinterpret_cast<float4*>(&ses[m][c4]) =
                *reinterpret_cast<const float4*>(&se[(size_t)(node0 + m) * EDGE_DIM + c4]);
    }
    if (tid < 64) {
        int nd = node0 + tid;
        if (nd < N) {
            dv[tid] = dinv[nd];
            od[tid] = (float)(row_out[nd + 1] - row_out[nd]);
        } else { dv[tid] = 0.f; od[tid] = 0.f; }
    }
    __syncthreads();

    float4 bna = *reinterpret_cast<const float4*>(&bnF[o0]);
    float4 bnb = *reinterpret_cast<const float4*>(&bnF[o0 + 4]);
    float4 bea = *reinterpret_cast<const float4*>(&beF[o0]);
    float4 beb = *reinterpret_cast<const float4*>(&beF[o0 + 4]);
    float4 acc[2][2];
#pragma unroll
    for (int i = 0; i < 2; i++) {
        float odv = od[m0 + i];
        acc[i][0] = make_float4(fmaf(odv, bea.x, bna.x), fmaf(odv, bea.y, bna.y),
                                fmaf(odv, bea.z, bna.z), fmaf(odv, bea.w, bna.w));
        acc[i][1] = make_float4(fmaf(odv, beb.x, bnb.x), fmaf(odv, beb.y, bnb.y),
                                fmaf(odv, beb.z, bnb.z), fmaf(odv, beb.w, bnb.w));
    }
    for (int k = 0; k < NODE_DIM; k += 4) {
        float4 xv0 = *reinterpret_cast<const float4*>(&xs[m0][k]);
        float4 xv1 = *reinterpret_cast<const float4*>(&xs[m0 + 1][k]);
        float x0v[4] = {xv0.x, xv0.y, xv0.z, xv0.w};
        float x1v[4] = {xv1.x, xv1.y, xv1.z, xv1.w};
#pragma unroll
        for (int j = 0; j < 4; j++) {
            float4 wa = *reinterpret_cast<const float4*>(&wn[k + j][o0]);
            float4 wb = *reinterpret_cast<const float4*>(&wn[k + j][o0 + 4]);
            f4_fma(acc[0][0], x0v[j], wa); f4_fma(acc[0][1], x0v[j], wb);
            f4_fma(acc[1][0], x1v[j], wa); f4_fma(acc[1][1], x1v[j], wb);
        }
    }
    for (int k = 0; k < EDGE_DIM; k += 4) {
        float4 sv0 = *reinterpret_cast<const float4*>(&ses[m0][k]);
        float4 sv1 = *reinterpret_cast<const float4*>(&ses[m0 + 1][k]);
        float s0v[4] = {sv0.x, sv0.y, sv0.z, sv0.w};
        float s1v[4] = {sv1.x, sv1.y, sv1.z, sv1.w};
#pragma unroll
        for (int j = 0; j < 4; j++) {
            float4 wa = *reinterpret_cast<const float4*>(&WeF[(k + j) * HDIM + o0]);
            float4 wb = *reinterpret_cast<const float4*>(&WeF[(k + j) * HDIM + o0 + 4]);
            f4_fma(acc[0][0], s0v[j], wa); f4_fma(acc[0][1], s0v[j], wb);
            f4_fma(acc[1][0], s1v[j], wa); f4_fma(acc[1][1], s1v[j], wb);
        }
    }
#pragma unroll
    for (int i = 0; i < 2; i++) {
        int node = node0 + m0 + i;
        if (node < N) {
            float d = dv[m0 + i];
            float4 r0 = acc[i][0], r1 = acc[i][1];
            r0.x *= d; r0.y *= d; r0.z *= d; r0.w *= d;
            r1.x *= d; r1.y *= d; r1.z *= d; r1.w *= d;
            *reinterpret_cast<float4*>(&gout[(size_t)node * HDIM + o0])     = r0;
            *reinterpret_cast<float4*>(&gout[(size_t)node * HDIM + o0 + 4]) = r1;
        }
    }
}

// ---- fused gather + next-layer matmul (8 slots x 8 lanes: 16 rows in flight) ----
__global__ __launch_bounds__(256) void k_gather_mm(const int* __restrict__ csr_src,
        const int* __restrict__ row_in, const float* __restrict__ gbuf,
        const float* __restrict__ bin, const float* __restrict__ dinv,
        const float* __restrict__ W, float* __restrict__ gout, int n) {
    __shared__ float hs[4][HDIM];
    int g = threadIdx.x >> 6, lane = threadIdx.x & 63;
    int slot = lane >> 3, dq8 = (lane & 7) * 8;
    int node = blockIdx.x * 4 + g;
    bool valid = node < n;
    float di = 0.f;
    float4 a0 = make_float4(0.f, 0.f, 0.f, 0.f);
    float4 a1 = make_float4(0.f, 0.f, 0.f, 0.f);
    if (valid) {
        di = dinv[node];
        if (slot == 0) {
            a0 = *reinterpret_cast<const float4*>(&gbuf[(size_t)node * HDIM + dq8]);
            a1 = *reinterpret_cast<const float4*>(&gbuf[(size_t)node * HDIM + dq8 + 4]);
        }
        int jb = row_in[node], je = row_in[node + 1];
        for (int base = jb; base < je; base += 64) {
            int cnt = min(64, je - base);
            int myidx = (base + lane < je) ? csr_src[base + lane] : 0;
            int t = 0;
#pragma unroll 2
            for (; t + 16 <= cnt; t += 16) {   // unpredicated: 2 rows/slot/iter
                int e0 = __shfl(myidx, t + slot, 64);
                int e1 = __shfl(myidx, t + 8 + slot, 64);
                const float* r0 = &gbuf[(size_t)e0 * HDIM + dq8];
                const float* r1 = &gbuf[(size_t)e1 * HDIM + dq8];
                float4 v00 = *reinterpret_cast<const float4*>(r0);
                float4 v01 = *reinterpret_cast<const float4*>(r0 + 4);
                float4 v10 = *reinterpret_cast<const float4*>(r1);
                float4 v11 = *reinterpret_cast<const float4*>(r1 + 4);
                f4_add(a0, v00); f4_add(a1, v01);
                f4_add(a0, v10); f4_add(a1, v11);
            }
            for (; t < cnt; t += 8) {          // predicated tail
                int which = t + slot;
                int e = __shfl(myidx, which, 64);
                if (which < cnt) {
                    const float* r = &gbuf[(size_t)e * HDIM + dq8];
                    f4_add(a0, *reinterpret_cast<const float4*>(r));
                    f4_add(a1, *reinterpret_cast<const float4*>(r + 4));
                }
            }
        }
        f4_shfl_xor_add(a0, 8);  f4_shfl_xor_add(a1, 8);
        f4_shfl_xor_add(a0, 16); f4_shfl_xor_add(a1, 16);
        f4_shfl_xor_add(a0, 32); f4_shfl_xor_add(a1, 32);
        if (slot == 0) {
            float4 b0 = *reinterpret_cast<const float4*>(&bin[dq8]);
            float4 b1 = *reinterpret_cast<const float4*>(&bin[dq8 + 4]);
            float4 z0, z1;
            z0.x = fmaxf(fmaf(di, a0.x, b0.x), 0.f);
            z0.y = fmaxf(fmaf(di, a0.y, b0.y), 0.f);
            z0.z = fmaxf(fmaf(di, a0.z, b0.z), 0.f);
            z0.w = fmaxf(fmaf(di, a0.w, b0.w), 0.f);
            z1.x = fmaxf(fmaf(di, a1.x, b1.x), 0.f);
            z1.y = fmaxf(fmaf(di, a1.y, b1.y), 0.f);
            z1.z = fmaxf(fmaf(di, a1.z, b1.z), 0.f);
            z1.w = fmaxf(fmaf(di, a1.w, b1.w), 0.f);
            *reinterpret_cast<float4*>(&hs[g][dq8])     = z0;
            *reinterpret_cast<float4*>(&hs[g][dq8 + 4]) = z1;
        }
    }
    __syncthreads();
    if (!valid) return;
    float a = 0.f;
#pragma unroll
    for (int k = 0; k < HDIM; k++) a = fmaf(hs[g][k], W[k * HDIM + lane], a);
    gout[(size_t)node * HDIM + lane] = a * di;
}

// ---- conv3 gather + finalize + mean-pool (8x8 decomposition, merged atomics) ----
__global__ __launch_bounds__(256) void k_gather_pool(const int* __restrict__ csr_src,
        const int* __restrict__ row_in, const float* __restrict__ gbuf,
        const float* __restrict__ bin, const float* __restrict__ dinv,
        const int* __restrict__ batch, float* __restrict__ sums,
        float* __restrict__ cnts, int n) {
    __shared__ float vs[4][HDIM];
    __shared__ int bs[4];
    int g = threadIdx.x >> 6, lane = threadIdx.x & 63;
    int slot = lane >> 3, dq8 = (lane & 7) * 8;
    int node = blockIdx.x * 4 + g;
    bool valid = node < n;
    float di = 0.f;
    int b = -1;
    float4 a0 = make_float4(0.f, 0.f, 0.f, 0.f);
    float4 a1 = make_float4(0.f, 0.f, 0.f, 0.f);
    if (valid) {
        di = dinv[node];
        b = batch[node];
        if (slot == 0) {
            a0 = *reinterpret_cast<const float4*>(&gbuf[(size_t)node * HDIM + dq8]);
            a1 = *reinterpret_cast<const float4*>(&gbuf[(size_t)node * HDIM + dq8 + 4]);
        }
        int jb = row_in[node], je = row_in[node + 1];
        for (int base = jb; base < je; base += 64) {
            int cnt = min(64, je - base);
            int myidx = (base + lane < je) ? csr_src[base + lane] : 0;
            int t = 0;
#pragma unroll 2
            for (; t + 16 <= cnt; t += 16) {
                int e0 = __shfl(myidx, t + slot, 64);
                int e1 = __shfl(myidx, t + 8 + slot, 64);
                const float* r0 = &gbuf[(size_t)e0 * HDIM + dq8];
                const float* r1 = &gbuf[(size_t)e1 * HDIM + dq8];
                float4 v00 = *reinterpret_cast<const float4*>(r0);
                float4 v01 = *reinterpret_cast<const float4*>(r0 + 4);
                float4 v10 = *reinterpret_cast<const float4*>(r1);
                float4 v11 = *reinterpret_cast<const float4*>(r1 + 4);
                f4_add(a0, v00); f4_add(a1, v01);
                f4_add(a0, v10); f4_add(a1, v11);
            }
            for (; t < cnt; t += 8) {
                int which = t + slot;
                int e = __shfl(myidx, which, 64);
                if (which < cnt) {
                    const float* r = &gbuf[(size_t)e * HDIM + dq8];
                    f4_add(a0, *reinterpret_cast<const float4*>(r));
                    f4_add(a1, *reinterpret_cast<const float4*>(r + 4));
                }
            }
        }
        f4_shfl_xor_add(a0, 8);  f4_shfl_xor_add(a1, 8);
        f4_shfl_xor_add(a0, 16); f4_shfl_xor_add(a1, 16);
        f4_shfl_xor_add(a0, 32); f4_shfl_xor_add(a1, 32);
        if (slot == 0) {
            float4 b0 = *reinterpret_cast<const float4*>(&bin[dq8]);
            float4 b1 = *reinterpret_cast<const float4*>(&bin[dq8 + 4]);
            float4 z0, z1;
            z0.x = fmaf(di, a0.x, b0.x); z0.y = fmaf(di, a0.y, b0.y);
            z0.z = fmaf(di, a0.z, b0.z); z0.w = fmaf(di, a0.w, b0.w);
            z1.x = fmaf(di, a1.x, b1.x); z1.y = fmaf(di, a1.y, b1.y);
            z1.z = fmaf(di, a1.z, b1.z); z1.w = fmaf(di, a1.w, b1.w);
            *reinterpret_cast<float4*>(&vs[g][dq8])     = z0;
            *reinterpret_cast<float4*>(&vs[g][dq8 + 4]) = z1;
        }
    }
    if (lane == 0) bs[g] = b;
    __syncthreads();
    bool same = (bs[0] >= 0 && bs[0] == bs[1] && bs[1] == bs[2] && bs[2] == bs[3]);
    if (same) {
        if (g == 0) {
            float t = vs[0][lane] + vs[1][lane] + vs[2][lane] + vs[3][lane];
            atomicAdd(&sums[(size_t)bs[0] * HDIM + lane], t);
            if (lane == 0) atomicAdd(&cnts[bs[0]], 4.0f);
        }
    } else if (valid) {
        atomicAdd(&sums[(size_t)b * HDIM + lane], vs[g][lane]);
        if (lane == 0) atomicAdd(&cnts[b], 1.0f);
    }
}

// ---- classifier ----
__global__ __launch_bounds__(64) void k_cls(const float* __restrict__ sums,
        const float* __restrict__ cnts, const float* __restrict__ W1,
        const float* __restrict__ b1, const float* __restrict__ W2,
        const float* __restrict__ b2, float* __restrict__ out) {
    __shared__ float gs[HDIM];
    __shared__ float zs[32];
    int b = blockIdx.x, t = threadIdx.x;
    float cnt = fmaxf(cnts[b], 1.0f);
    gs[t] = sums[(size_t)b * HDIM + t] / cnt;
    __syncthreads();
    if (t < 32) {
        float a = b1[t];
#pragma unroll
        for (int k = 0; k < HDIM; k++) a = fmaf(gs[k], W1[k * 32 + t], a);
        zs[t] = fmaxf(a, 0.0f);
    }
    __syncthreads();
    if (t == 0) {
        float a = b2[0];
#pragma unroll
        for (int k = 0; k < 32; k++) a = fmaf(zs[k], W2[k], a);
        out[b] = a;
    }
}

extern "C" void kernel_launch(void* const* d_in, const int* in_sizes, int n_in,
                              void* d_out, int out_size, void* d_ws, size_t ws_size,
                              hipStream_t stream) {
    const float* x      = (const float*)d_in[0];
    const int*   ei     = (const int*)d_in[1];
    const float* ea     = (const float*)d_in[2];
    const int*   batch  = (const int*)d_in[3];
    const float* W_node = (const float*)d_in[4];
    const float* b_node = (const float*)d_in[5];
    const float* W_edge = (const float*)d_in[6];
    const float* b_edge = (const float*)d_in[7];
    const float* W_g1   = (const float*)d_in[8];
    const float* b_g1   = (const float*)d_in[9];
    const float* W_g2   = (const float*)d_in[10];
    const float* b_g2   = (const float*)d_in[11];
    const float* W_g3   = (const float*)d_in[12];
    const float* b_g3   = (const float*)d_in[13];
    const float* W_c1   = (const float*)d_in[14];
    const float* b_c1   = (const float*)d_in[15];
    const float* W_c2   = (const float*)d_in[16];
    const float* b_c2   = (const float*)d_in[17];

    const int N = in_sizes[0] / NODE_DIM;
    const int E = in_sizes[2] / EDGE_DIM;
    const int G = out_size;
    const int W = (N + NB - 1) / NB;
    const int* src = ei;
    const int* dst = ei + E;

    char* ws = (char*)d_ws;
    size_t off = 0;
    auto carve = [&](size_t bytes) -> void* {
        void* p = ws + off;
        off += (bytes + 255) & ~(size_t)255;
        return p;
    };
    int*   counts     = (int*)carve((size_t)2 * NB * 4);
    int*   baseD      = (int*)carve((size_t)(NB + 1) * 4);
    int*   baseS      = (int*)carve((size_t)(NB + 1) * 4);
    int*   curD       = (int*)carve((size_t)NB * 4);
    int*   curS       = (int*)carve((size_t)NB * 4);
    int*   row_in     = (int*)carve((size_t)(N + 1) * 4);
    int*   row_out    = (int*)carve((size_t)(N + 1) * 4);
    int*   csr_in_src = (int*)carve((size_t)E * 4);
    int*   csr_out_e  = (int*)carve((size_t)E * 4);
    float* dinv       = (float*)carve((size_t)N * 4);
    float* se         = (float*)carve((size_t)N * EDGE_DIM * 4);
    float* B          = (float*)carve((size_t)N * HDIM * 4);
    float* C          = (float*)carve((size_t)N * HDIM * 4);
    float* sums       = (float*)carve((size_t)G * HDIM * 4);
    float* cnts       = (float*)carve((size_t)G * 4);
    float* WnF        = (float*)carve((size_t)NODE_DIM * HDIM * 4);
    float* WeF        = (float*)carve((size_t)EDGE_DIM * HDIM * 4);
    float* bnF        = (float*)carve((size_t)HDIM * 4);
    float* beF        = (float*)carve((size_t)HDIM * 4);
    int*   countD = counts, *countS = counts + NB;
    unsigned* pairD = (unsigned*)B;   // aliases B (consumed before B first written)
    unsigned* pairS = (unsigned*)C;   // aliases C

    hipMemsetAsync(counts, 0, (size_t)2 * NB * 4, stream);
    hipMemsetAsync(sums, 0, (size_t)G * HDIM * 4, stream);
    hipMemsetAsync(cnts, 0, (size_t)G * 4, stream);

    const int nb_nodes = (N + 3) / 4;
    const int nb_bin   = (E + EPB - 1) / EPB;
    const int nb_t64   = (N + 63) / 64;

    // fold W_g1 into the embed weights (independent of graph build)
    k_foldw<<<((NODE_DIM + EDGE_DIM + 2) * HDIM + 255) / 256, 256, 0, stream>>>(
        W_node, W_edge, b_node, b_edge, W_g1, WnF, WeF, bnF, beF);

    // CSR construction via bucket binning (packed pairs, merged build)
    k_bin_count<<<nb_bin, 512, 0, stream>>>(src, dst, countD, countS, E, W);
    k_bucket_scan<<<1, 256, 0, stream>>>(countD, countS, baseD, baseS, curD, curS, E);
    k_bin_scatter<<<nb_bin, 512, 0, stream>>>(src, dst, curD, curS, pairD, pairS, E, W);
    k_build2<<<2 * NB, 256, 0, stream>>>(pairD, pairS, baseD, baseS,
                                         csr_in_src, csr_out_e, row_in, row_out,
                                         dinv, N, W);

    // edge-attr segment sum, then W-in-LDS fused embed (+folded mm1) -> B (g1)
    k_edge_sum<<<nb_nodes, 256, 0, stream>>>(ea, csr_out_e, row_out, se, N);
    k_embed_g1w<<<nb_t64, 256, 0, stream>>>(x, se, row_out, dinv, WnF, WeF, bnF, beF,
                                            B, N);

    // conv1 gather + mm2 -> C (g2); conv2 gather + mm3 -> B (g3)
    k_gather_mm<<<nb_nodes, 256, 0, stream>>>(csr_in_src, row_in, B, b_g1, dinv,
                                              W_g2, C, N);
    k_gather_mm<<<nb_nodes, 256, 0, stream>>>(csr_in_src, row_in, C, b_g2, dinv,
                                              W_g3, B, N);

    // conv3 gather + finalize + pool, then classifier
    k_gather_pool<<<nb_nodes, 256, 0, stream>>>(csr_in_src, row_in, B, b_g3,
                                                dinv, batch, sums, cnts, N);
    k_cls<<<G, 64, 0, stream>>>(sums, cnts, W_c1, b_c1, W_c2, b_c2, (float*)d_out);
}